// Round 1
// baseline (542.480 us; speedup 1.0000x reference)
//
#include <hip/hip_runtime.h>
#include <hip/hip_bf16.h>
#include <stdint.h>

#define IN_F   4096
#define OUT_F  4096
#define M_TOT  8192   // 4 * 2048

typedef __bf16 bf16x8 __attribute__((ext_vector_type(8)));
typedef float  floatx4 __attribute__((ext_vector_type(4)));

__device__ __forceinline__ unsigned short f2bf_bits(float f) {
    union { float f; uint32_t u; } v; v.f = f;
    uint32_t r = v.u + 0x7FFF + ((v.u >> 16) & 1);   // RNE
    return (unsigned short)(r >> 16);
}

__device__ __forceinline__ void gl_lds16(const void* g, void* l) {
    __builtin_amdgcn_global_load_lds(
        (const __attribute__((address_space(1))) void*)g,
        (__attribute__((address_space(3))) void*)l, 16, 0, 0);
}

// ---- x: fp32 -> bf16, 4 elements/thread ----
__global__ void cvt_x_kernel(const float* __restrict__ x, ushort* __restrict__ xb) {
    int i = blockIdx.x * blockDim.x + threadIdx.x;
    float4 v = reinterpret_cast<const float4*>(x)[i];
    ushort4 o;
    o.x = f2bf_bits(v.x); o.y = f2bf_bits(v.y);
    o.z = f2bf_bits(v.z); o.w = f2bf_bits(v.w);
    reinterpret_cast<ushort4*>(xb)[i] = o;
}

// ---- W: packed int4 -> bf16, 4 packed (8 weights)/thread; all 8 in one group ----
__global__ void dequant_kernel(const int* __restrict__ packed,
                               const float* __restrict__ scales,
                               const float* __restrict__ offsets,
                               ushort* __restrict__ wb) {
    int i = blockIdx.x * blockDim.x + threadIdx.x;   // chunk of 4 packed ints
    int4 p = reinterpret_cast<const int4*>(packed)[i];
    int g = i >> 4;                                  // (8*i)/128
    float s = scales[g], off = offsets[g];
    uint4 ov;
    {
        int pv = p.x;
        unsigned w0 = f2bf_bits((float)(pv & 0xF) * s + off);
        unsigned w1 = f2bf_bits((float)((pv >> 4) & 0xF) * s + off);
        ov.x = w0 | (w1 << 16);
    }
    {
        int pv = p.y;
        unsigned w0 = f2bf_bits((float)(pv & 0xF) * s + off);
        unsigned w1 = f2bf_bits((float)((pv >> 4) & 0xF) * s + off);
        ov.y = w0 | (w1 << 16);
    }
    {
        int pv = p.z;
        unsigned w0 = f2bf_bits((float)(pv & 0xF) * s + off);
        unsigned w1 = f2bf_bits((float)((pv >> 4) & 0xF) * s + off);
        ov.z = w0 | (w1 << 16);
    }
    {
        int pv = p.w;
        unsigned w0 = f2bf_bits((float)(pv & 0xF) * s + off);
        unsigned w1 = f2bf_bits((float)((pv >> 4) & 0xF) * s + off);
        ov.w = w0 | (w1 << 16);
    }
    reinterpret_cast<uint4*>(wb)[i] = ov;
}

// ---- GEMM: C[M_TOT][OUT_F] = A[M_TOT][IN_F] * B[OUT_F][IN_F]^T + bias ----
// 128x128 tile, BK=32, 256 threads (2x2 waves, each 64x64 via 4x4 MFMA 16x16x32)
__global__ void gemm_kernel(const ushort* __restrict__ A,   // bf16 [M_TOT][IN_F]
                            const ushort* __restrict__ B,   // bf16 [OUT_F][IN_F]
                            const float* __restrict__ bias,
                            float* __restrict__ C) {
    __shared__ __align__(16) ushort As[128 * 32];
    __shared__ __align__(16) ushort Bs[128 * 32];

    const int tid  = threadIdx.x;
    const int wave = tid >> 6;
    const int lane = tid & 63;
    const int quad = lane >> 4;
    const int l16  = lane & 15;
    const int wm   = wave >> 1;
    const int wn   = wave & 1;

    const int bm = blockIdx.y;
    const int bn = blockIdx.x;

    // staging: chunk c = issue*256 + tid maps to LDS bytes [c*16, c*16+16)
    // row = c>>2 (tile row), kk = (c&3)*8 (k element offset)
    const int c0 = tid, c1 = 256 + tid;
    const int rA0 = c0 >> 2, kA0 = (c0 & 3) << 3;
    const int rA1 = c1 >> 2, kA1 = (c1 & 3) << 3;

    const ushort* gA0 = A + (size_t)(bm * 128 + rA0) * IN_F + kA0;
    const ushort* gA1 = A + (size_t)(bm * 128 + rA1) * IN_F + kA1;
    const ushort* gB0 = B + (size_t)(bn * 128 + rA0) * IN_F + kA0;
    const ushort* gB1 = B + (size_t)(bn * 128 + rA1) * IN_F + kA1;

    // wave-uniform LDS destinations: base = issue*4096 + wave*1024 bytes
    char* lA0 = (char*)As + wave * 1024;
    char* lA1 = (char*)As + 4096 + wave * 1024;
    char* lB0 = (char*)Bs + wave * 1024;
    char* lB1 = (char*)Bs + 4096 + wave * 1024;

    floatx4 acc[4][4] = {};

    const int arow = wm * 64 + l16;   // + mi*16
    const int brow = wn * 64 + l16;   // + ni*16
    const int koff = quad * 8;

    for (int k0 = 0; k0 < IN_F; k0 += 32) {
        gl_lds16(gA0, lA0);
        gl_lds16(gA1, lA1);
        gl_lds16(gB0, lB0);
        gl_lds16(gB1, lB1);
        gA0 += 32; gA1 += 32; gB0 += 32; gB1 += 32;
        __syncthreads();

        bf16x8 af[4], bfr[4];
#pragma unroll
        for (int mi = 0; mi < 4; ++mi)
            af[mi] = *reinterpret_cast<const bf16x8*>(&As[(arow + mi * 16) * 32 + koff]);
#pragma unroll
        for (int ni = 0; ni < 4; ++ni)
            bfr[ni] = *reinterpret_cast<const bf16x8*>(&Bs[(brow + ni * 16) * 32 + koff]);

#pragma unroll
        for (int mi = 0; mi < 4; ++mi)
#pragma unroll
            for (int ni = 0; ni < 4; ++ni)
                acc[mi][ni] = __builtin_amdgcn_mfma_f32_16x16x32_bf16(
                    af[mi], bfr[ni], acc[mi][ni], 0, 0, 0);

        __syncthreads();
    }

    // epilogue: D lane mapping col = l16, row = quad*4 + r
    const float* biasp = bias + bn * 128 + wn * 64 + l16;
    float* Cp = C + (size_t)(bm * 128 + wm * 64 + quad * 4) * OUT_F + bn * 128 + wn * 64 + l16;
#pragma unroll
    for (int mi = 0; mi < 4; ++mi) {
#pragma unroll
        for (int ni = 0; ni < 4; ++ni) {
            float bv = biasp[ni * 16];
#pragma unroll
            for (int r = 0; r < 4; ++r)
                Cp[(size_t)(mi * 16 + r) * OUT_F + ni * 16] = acc[mi][ni][r] + bv;
        }
    }
}

extern "C" void kernel_launch(void* const* d_in, const int* in_sizes, int n_in,
                              void* d_out, int out_size, void* d_ws, size_t ws_size,
                              hipStream_t stream) {
    const float* x       = (const float*)d_in[0];
    const int*   packed  = (const int*)d_in[1];
    const float* scales  = (const float*)d_in[2];
    const float* offsets = (const float*)d_in[3];
    const float* bias    = (const float*)d_in[4];
    float* out = (float*)d_out;

    ushort* xb = (ushort*)d_ws;                                   // 8192*4096*2  = 64 MiB
    ushort* wb = (ushort*)((char*)d_ws + (size_t)M_TOT * IN_F * 2); // 4096*4096*2 = 32 MiB

    // x: 33,554,432 elems / 4 per thread / 256 per block = 32768 blocks
    cvt_x_kernel<<<32768, 256, 0, stream>>>(x, xb);
    // packed: 8,388,608 elems / 4 per thread / 256 = 8192 blocks
    dequant_kernel<<<8192, 256, 0, stream>>>(packed, scales, offsets, wb);

    dim3 grid(OUT_F / 128, M_TOT / 128);   // (32, 64)
    gemm_kernel<<<grid, 256, 0, stream>>>(xb, wb, bias, out);
}